// Round 18
// baseline (2683.438 us; speedup 1.0000x reference)
//
#include <hip/hip_runtime.h>

#define DEV __device__ __forceinline__

typedef __bf16 bf16x8 __attribute__((ext_vector_type(8)));
typedef float f32x4 __attribute__((ext_vector_type(4)));

DEV unsigned short f2bf(float f) {
  union { float f; unsigned u; } v; v.f = f;
  unsigned r = v.u + 0x7FFFu + ((v.u >> 16) & 1u);
  return (unsigned short)(r >> 16);
}
DEV float bf2f(unsigned short h) {
  union { float f; unsigned u; } v; v.u = ((unsigned)h) << 16;
  return v.f;
}

// async global->LDS, 16B per lane.
DEV void gload16(const void* g, void* l) {
  __builtin_amdgcn_global_load_lds(
      (__attribute__((address_space(1))) void*)(g),
      (__attribute__((address_space(3))) void*)(l), 16, 0, 0);
}

#define MFMA16(a, b, c) __builtin_amdgcn_mfma_f32_16x16x32_bf16((a), (b), (c), 0, 0, 0)

// ---------------------------------------------------------------------------
// Persistent 256x256 GEMM (PROVEN round-5 k-loop; persistent wrapper from
// round 13). Do not touch.
// ---------------------------------------------------------------------------
struct TileCtx {
  const char* gA;
  const char* gB;
  size_t stepA, stepB;
  const float* bias;
  unsigned short* Out;
  int nkt, ldo, n0, m0;
};

DEV TileCtx tile_decode(int bid, int nwg,
    const unsigned short* A, const unsigned short* Bt, const float* bias,
    unsigned short* Out, int K, int lda, int ldo, int nbx, int nby,
    long sA, long sB, long sBias, long sOut, int rr, int ch)
{
  int wg = bid;
  {
    const int q = nwg >> 3, r = nwg & 7;
    const int xcd = wg & 7, pos = wg >> 3;
    wg = (xcd < r ? xcd * (q + 1) : r * (q + 1) + (xcd - r) * q) + pos;
  }
  const int per_z = nbx * nby;
  const int z  = wg / per_z;
  const int rz = wg - z * per_z;
  const int by = rz / nbx;
  const int bx = rz - by * nbx;

  TileCtx c;
  c.nkt = K >> 6;
  c.ldo = ldo;
  c.m0  = by * 256;
  c.n0  = bx * 256;
  c.bias = bias + (size_t)z * sBias;
  c.Out  = Out  + (size_t)z * sOut;
  c.gA = (const char*)(A  + (size_t)z * sA) + ((size_t)(c.m0 + rr) * lda) * 2 + ch * 16;
  c.gB = (const char*)(Bt + (size_t)z * sB) + ((size_t)(c.n0 + rr) * K)   * 2 + ch * 16;
  c.stepA = (size_t)64 * lda * 2;
  c.stepB = (size_t)64 * K * 2;
  return c;
}

DEV void gemm_persist(
    const unsigned short* A1, const unsigned short* Bt1, const float* bias1,
    unsigned short* O1, int K1, int lda1, int ldo1, int nbx1, int nby1,
    long sA1, long sB1, long sBias1, long sO1,
    const unsigned short* A2, const unsigned short* Bt2, const float* bias2,
    unsigned short* O2, int K2, int lda2, int ldo2, int nbx2, int nby2,
    long sA2, long sB2, long sBias2, long sO2,
    int split, int total)
{
  __shared__ alignas(16) char sm[2][65536];
  char* smb = &sm[0][0];

  const int tid  = threadIdx.x;
  const int lane = tid & 63;
  const int wid  = tid >> 6;
  const int wm   = wid >> 2, wn = wid & 3;
  const int rr = tid >> 3;
  const int ch = (tid & 7) ^ (rr & 7);
  const int koff0 = (((lane >> 4) << 4) ^ ((lane & 7) << 4));
  const int aRow  = wm * 128 + (lane & 15);
  const int bRow  = wn * 64  + (lane & 15);

  auto dec = [&](int tix) -> TileCtx {
    if (tix < split)
      return tile_decode(tix, split, A1, Bt1, bias1, O1, K1, lda1, ldo1,
                         nbx1, nby1, sA1, sB1, sBias1, sO1, rr, ch);
    return tile_decode(tix - split, total - split, A2, Bt2, bias2, O2, K2,
                       lda2, ldo2, nbx2, nby2, sA2, sB2, sBias2, sO2, rr, ch);
  };
  auto SA = [&](const TileCtx& c, int buf, int kt, int jh) {
    const char* s = c.gA + (size_t)kt * 128 + (2 * jh) * c.stepA;
    char* l = smb + buf * 65536 + tid * 16 + (2 * jh) * 8192;
    gload16(s, l);
    gload16(s + c.stepA, l + 8192);
  };
  auto SB = [&](const TileCtx& c, int buf, int kt, int jh) {
    const char* s = c.gB + (size_t)kt * 128 + (2 * jh) * c.stepB;
    char* l = smb + buf * 65536 + 32768 + tid * 16 + (2 * jh) * 8192;
    gload16(s, l);
    gload16(s + c.stepB, l + 8192);
  };
  auto STAGE0 = [&](const TileCtx& c) {
    SA(c, 0, 0, 0); SA(c, 0, 0, 1); SB(c, 0, 0, 0); SB(c, 0, 0, 1);
  };

  int tix = (int)blockIdx.x;
  if (tix >= total) return;
  TileCtx cur = dec(tix);
  STAGE0(cur);

  f32x4 acc[8][4];
  const f32x4 fz = {0.f, 0.f, 0.f, 0.f};

  while (true) {
#pragma unroll
    for (int i = 0; i < 8; ++i)
#pragma unroll
      for (int j = 0; j < 4; ++j) acc[i][j] = fz;

    const int nkt = cur.nkt;
    for (int kt = 0; kt < nkt; ++kt) {
      const int cb = kt & 1, nb = cb ^ 1;
      const bool pre = (kt + 1 < nkt);
      if (pre) {
        SA(cur, nb, kt + 1, 0);
        asm volatile("s_waitcnt vmcnt(2)" ::: "memory");
      } else {
        asm volatile("s_waitcnt vmcnt(0)" ::: "memory");
      }
      __builtin_amdgcn_s_barrier();
      __builtin_amdgcn_sched_barrier(0);

      const char* pA = smb + cb * 65536 + aRow * 128;
      const char* pB = smb + cb * 65536 + 32768 + bRow * 128;
      bf16x8 a0[4], a1[4], b0[4], b1[4];

      // ---- phase 0: mi 0-3, ks0
      {
#pragma unroll
        for (int i = 0; i < 4; ++i) a0[i] = *(const bf16x8*)(pA + i * 2048 + koff0);
#pragma unroll
        for (int n = 0; n < 4; ++n) b0[n] = *(const bf16x8*)(pB + n * 2048 + koff0);
        if (pre) SA(cur, nb, kt + 1, 1);
        asm volatile("s_waitcnt lgkmcnt(0)" ::: "memory");
        __builtin_amdgcn_sched_barrier(0);
        __builtin_amdgcn_s_setprio(1);
#pragma unroll
        for (int i = 0; i < 4; ++i)
#pragma unroll
          for (int n = 0; n < 4; ++n) acc[i][n] = MFMA16(a0[i], b0[n], acc[i][n]);
        __builtin_amdgcn_s_setprio(0);
        __builtin_amdgcn_sched_barrier(0);
        __builtin_amdgcn_s_barrier();
        __builtin_amdgcn_sched_barrier(0);
      }
      // ---- phase 1: mi 4-7, ks0
      {
#pragma unroll
        for (int i = 0; i < 4; ++i) a1[i] = *(const bf16x8*)(pA + (i + 4) * 2048 + koff0);
        if (pre) { SB(cur, nb, kt + 1, 0); SB(cur, nb, kt + 1, 1); }
        asm volatile("s_waitcnt lgkmcnt(0)" ::: "memory");
        __builtin_amdgcn_sched_barrier(0);
        __builtin_amdgcn_s_setprio(1);
#pragma unroll
        for (int i = 0; i < 4; ++i)
#pragma unroll
          for (int n = 0; n < 4; ++n) acc[i + 4][n] = MFMA16(a1[i], b0[n], acc[i + 4][n]);
        __builtin_amdgcn_s_setprio(0);
        __builtin_amdgcn_sched_barrier(0);
        __builtin_amdgcn_s_barrier();
        __builtin_amdgcn_sched_barrier(0);
      }
      // ---- phase 2: mi 0-3, ks1
      {
        const int ko = koff0 ^ 64;
#pragma unroll
        for (int i = 0; i < 4; ++i) a0[i] = *(const bf16x8*)(pA + i * 2048 + ko);
#pragma unroll
        for (int n = 0; n < 4; ++n) b1[n] = *(const bf16x8*)(pB + n * 2048 + ko);
        asm volatile("s_waitcnt lgkmcnt(0)" ::: "memory");
        __builtin_amdgcn_sched_barrier(0);
        __builtin_amdgcn_s_setprio(1);
#pragma unroll
        for (int i = 0; i < 4; ++i)
#pragma unroll
          for (int n = 0; n < 4; ++n) acc[i][n] = MFMA16(a0[i], b1[n], acc[i][n]);
        __builtin_amdgcn_s_setprio(0);
        __builtin_amdgcn_sched_barrier(0);
        __builtin_amdgcn_s_barrier();
        __builtin_amdgcn_sched_barrier(0);
      }
      // ---- phase 3: mi 4-7, ks1
      {
        const int ko = koff0 ^ 64;
#pragma unroll
        for (int i = 0; i < 4; ++i) a1[i] = *(const bf16x8*)(pA + (i + 4) * 2048 + ko);
        asm volatile("s_waitcnt lgkmcnt(0)" ::: "memory");
        __builtin_amdgcn_sched_barrier(0);
        __builtin_amdgcn_s_setprio(1);
#pragma unroll
        for (int i = 0; i < 4; ++i)
#pragma unroll
          for (int n = 0; n < 4; ++n) acc[i + 4][n] = MFMA16(a1[i], b1[n], acc[i + 4][n]);
        __builtin_amdgcn_s_setprio(0);
        __builtin_amdgcn_sched_barrier(0);
        __builtin_amdgcn_s_barrier();
        __builtin_amdgcn_sched_barrier(0);
      }
    }

    // cross-tile prefetch before the epilogue stores
    const int nxt = tix + (int)gridDim.x;
    const bool has = nxt < total;
    TileCtx nc;
    if (has) { nc = dec(nxt); STAGE0(nc); }

    // epilogue: bias + lrelu + bf16 store
#pragma unroll
    for (int ni = 0; ni < 4; ++ni) {
      const int c = cur.n0 + wn * 64 + ni * 16 + (lane & 15);
      const float bv = cur.bias[c];
#pragma unroll
      for (int mi = 0; mi < 8; ++mi) {
        const int r0 = cur.m0 + wm * 128 + mi * 16 + ((lane >> 4) << 2);
#pragma unroll
        for (int j = 0; j < 4; ++j) {
          float v = acc[mi][ni][j] + bv;
          v = v >= 0.f ? v : 0.1f * v;
          cur.Out[(size_t)(r0 + j) * cur.ldo + c] = f2bf(v);
        }
      }
    }

    if (!has) return;
    cur = nc;
    tix = nxt;
  }
}

__global__ __launch_bounds__(512) void gemm_dual(
    const unsigned short* A1, const unsigned short* Bt1, const float* bias1,
    unsigned short* O1, int K1, int lda1, int ldo1, int nbx1, int nby1,
    long sA1, long sB1, long sBias1, long sO1,
    const unsigned short* A2, const unsigned short* Bt2, const float* bias2,
    unsigned short* O2, int K2, int lda2, int ldo2, int nbx2, int nby2,
    long sA2, long sB2, long sBias2, long sO2,
    int split, int total)
{
  gemm_persist(A1, Bt1, bias1, O1, K1, lda1, ldo1, nbx1, nby1,
               sA1, sB1, sBias1, sO1,
               A2, Bt2, bias2, O2, K2, lda2, ldo2, nbx2, nby2,
               sA2, sB2, sBias2, sO2, split, total);
}

#define GEMM_DEF(NAME)                                                        \
__global__ __launch_bounds__(512) void NAME(                                  \
    const unsigned short* A, const unsigned short* Bt, const float* bias,     \
    unsigned short* Out, int K, int lda, int ldo, int nbx, int nby,           \
    long sA, long sB, long sBias, long sOut, int total) {                     \
  gemm_persist(A, Bt, bias, Out, K, lda, ldo, nbx, nby, sA, sB, sBias, sOut,  \
               A, Bt, bias, Out, K, lda, ldo, nbx, nby, sA, sB, sBias, sOut,  \
               total, total);                                                 \
}
GEMM_DEF(gemm_l3)
GEMM_DEF(gemm_tw)

// ---------------------------------------------------------------------------
// gate bias gather (concatenated column space: sh20|sa12|ra12|ea12, pad 0)
// ---------------------------------------------------------------------------
DEV float gateB(const float* bsh, const float* bsa, const float* bra,
                const float* bea, int c) {
  if (c < 20) return bsh[c];
  if (c < 32) return bsa[c - 20];
  if (c < 44) return bra[c - 32];
  if (c < 56) return bea[c - 44];
  return 0.f;
}

// ---------------------------------------------------------------------------
// prep_all: gate logits + all fp32->bf16 conversions in ONE launch.
//   [0,128):         gate logits — fp32 micro-GEMM, hoisted W pointers +
//                    register prefetch of next K-tile
//   [128,12288):     weight transposes — 2 k-tiles per block, two-phase LDS
//   [12288,13312):   x straight convert, 2 tiles per block
// ---------------------------------------------------------------------------
__global__ __launch_bounds__(256) void prep_all(
    const float* __restrict__ W1,  const float* __restrict__ W2,
    const float* __restrict__ W3,  const float* __restrict__ Wt1,
    const float* __restrict__ Wt2, const float* __restrict__ x,
    const float* __restrict__ Wsh, const float* __restrict__ bsh,
    const float* __restrict__ Wsa, const float* __restrict__ bsa,
    const float* __restrict__ Wra, const float* __restrict__ bra,
    const float* __restrict__ Wea, const float* __restrict__ bea,
    unsigned short* __restrict__ W1t,  unsigned short* __restrict__ W2t,
    unsigned short* __restrict__ W3t,  unsigned short* __restrict__ Wt1t,
    unsigned short* __restrict__ Wt2t, unsigned short* __restrict__ xb,
    float* __restrict__ logits)
{
  const int id = blockIdx.x;
  const int t  = threadIdx.x;

  if (id < 128) {
    __shared__ alignas(16) float smg[4096];          // sx[32][64] | sw[32][64]
    float (*sx)[64] = (float (*)[64])smg;
    float (*sw)[64] = (float (*)[64])(smg + 2048);
    const int b0 = id * 64;
    const int tr = t >> 4, tc = t & 15;

    const int xr = t >> 3;
    const int xc = (t & 7) * 4;
    const int c4 = tc * 4;
    const float* wb = Wsh; int wo = 0, gw = 20; bool wval = true;
    if (c4 < 20)      { wb = Wsh; wo = c4;      gw = 20; }
    else if (c4 < 32) { wb = Wsa; wo = c4 - 20; gw = 12; }
    else if (c4 < 44) { wb = Wra; wo = c4 - 32; gw = 12; }
    else if (c4 < 56) { wb = Wea; wo = c4 - 44; gw = 12; }
    else              { wval = false; }
    const int wr0 = t >> 4;

    float4 xv0, xv1;
    float w0[4], w1[4];
    auto ldx = [&](int k0) {
      xv0 = *(const float4*)(x + (size_t)(b0 + xr) * 1024 + k0 + xc);
      xv1 = *(const float4*)(x + (size_t)(b0 + 32 + xr) * 1024 + k0 + xc);
    };
    auto ldw = [&](int k0) {
#pragma unroll
      for (int j = 0; j < 4; ++j) {
        w0[j] = wval ? wb[(size_t)(k0 + wr0) * gw + wo + j] : 0.f;
        w1[j] = wval ? wb[(size_t)(k0 + 16 + wr0) * gw + wo + j] : 0.f;
      }
    };
    ldx(0); ldw(0);

    float acc[4][4] = {};
    for (int kt = 0; kt < 32; ++kt) {
      __syncthreads();
      sx[xc + 0][xr] = xv0.x; sx[xc + 1][xr] = xv0.y;
      sx[xc + 2][xr] = xv0.z; sx[xc + 3][xr] = xv0.w;
      sx[xc + 0][32 + xr] = xv1.x; sx[xc + 1][32 + xr] = xv1.y;
      sx[xc + 2][32 + xr] = xv1.z; sx[xc + 3][32 + xr] = xv1.w;
#pragma unroll
      for (int j = 0; j < 4; ++j) {
        sw[wr0][c4 + j]      = w0[j];
        sw[16 + wr0][c4 + j] = w1[j];
      }
      if (kt + 1 < 32) { ldx((kt + 1) * 32); ldw((kt + 1) * 32); }
      __syncthreads();
#pragma unroll
      for (int kk = 0; kk < 32; ++kk) {
        const float4 rx = *(const float4*)&sx[kk][tr * 4];
        const float4 wv = *(const float4*)&sw[kk][tc * 4];
#pragma unroll
        for (int i = 0; i < 4; ++i) {
          const float xv = (i == 0) ? rx.x : (i == 1) ? rx.y : (i == 2) ? rx.z : rx.w;
          acc[i][0] += xv * wv.x; acc[i][1] += xv * wv.y;
          acc[i][2] += xv * wv.z; acc[i][3] += xv * wv.w;
        }
      }
    }
    float bv[4];
#pragma unroll
    for (int j = 0; j < 4; ++j) bv[j] = gateB(bsh, bsa, bra, bea, c4 + j);
#pragma unroll
    for (int i = 0; i < 4; ++i) {
      float4 o;
      o.x = acc[i][0] + bv[0]; o.y = acc[i][1] + bv[1];
      o.z = acc[i][2] + bv[2]; o.w = acc[i][3] + bv[3];
      *(float4*)&logits[(size_t)(b0 + tr * 4 + i) * 64 + tc * 4] = o;
    }
    return;
  }

  if (id >= 12288) {                 // x straight convert, 2 tiles/block
    const int base = (id - 12288) * 2;
#pragma unroll
    for (int jj = 0; jj < 2; ++jj) {
      const int lt = base + jj;
      const int r0 = (lt >> 4) * 64, c0 = (lt & 15) * 64;
#pragma unroll
      for (int i = 0; i < 4; ++i) {
        const int row = r0 + i * 16 + (t >> 4);
        const int col = c0 + (t & 15) * 4;
        const float4 v = *(const float4*)(x + (size_t)row * 1024 + col);
        ushort4 u = make_ushort4(f2bf(v.x), f2bf(v.y), f2bf(v.z), f2bf(v.w));
        *(ushort4*)(xb + (size_t)row * 1024 + col) = u;
      }
    }
    return;
  }

  // ---- weight transposes: 2 k-tiles (128 k-rows x 64 n-cols) per block
  const int g = id - 128;
  const float* src; unsigned short* dst; int K, N, local;
  if (g < 5120)       { src = W1;  dst = W1t;  K = 1024; N = 2048; local = g; }
  else if (g < 10240) { src = W2;  dst = W2t;  K = 2048; N = 1024; local = g - 5120; }
  else if (g < 11520) { src = W3;  dst = W3t;  K = 1024; N = 512;  local = g - 10240; }
  else if (g < 12032) { src = Wt1; dst = Wt1t; K = 2048; N = 1024; local = g - 11520; }
  else                { src = Wt2; dst = Wt2t; K = 1024; N = 512;  local = g - 12032; }

  const int npk = K >> 7, nnt = N >> 6;
  const int per_z = npk * nnt;
  const int z   = local / per_z;
  const int rem = local - z * per_z;
  const int pk  = rem % npk;
  const int n0  = (rem / npk) * 64;
  src += (size_t)z * K * N;
  dst += (size_t)z * K * N;

  __shared__ unsigned short ldsT[64 * 65];
  const int cr = t >> 4, cc = (t & 15) * 4;
  const int nrow = t >> 2, ks = (t & 3) * 16;
#pragma unroll
  for (int jj = 0; jj < 2; ++jj) {
    const int k0 = pk * 128 + jj * 64;
    if (jj) __syncthreads();
#pragma unroll
    for (int i = 0; i < 4; ++i) {
      const int row = i * 16 + cr;
      const float4 v = *(const float4*)(src + (size_t)(k0 + row) * N + n0 + cc);
      ldsT[(cc + 0) * 65 + row] = f2bf(v.x);
      ldsT[(cc + 1) * 65 + row] = f2bf(v.y);
      ldsT[(cc + 2) * 65 + row] = f2bf(v.z);
      ldsT[(cc + 3) * 65 + row] = f2bf(v.w);
    }
    __syncthreads();
    unsigned short vbuf[16];
#pragma unroll
    for (int j = 0; j < 16; ++j) vbuf[j] = ldsT[nrow * 65 + ks + j];
    unsigned short* dp = dst + (size_t)(n0 + nrow) * K + k0 + ks;
    *(uint4*)dp       = *(const uint4*)&vbuf[0];
    *(uint4*)(dp + 8) = *(const uint4*)&vbuf[8];
  }
}

// ---------------------------------------------------------------------------
// combine: async eo-row staging overlapped with softmax, then gated sums.
// ---------------------------------------------------------------------------
__global__ __launch_bounds__(256) void combine_k(
    const unsigned short* __restrict__ eo,   // [8192][10240]
    const float* __restrict__ logits,        // [8192][64]
    unsigned short* __restrict__ tin)        // [8192][2048]
{
  const int b = blockIdx.x;
  const int t = threadIdx.x;
  __shared__ alignas(16) unsigned short lds[20][512];
  __shared__ float gsm[56];
  const unsigned short* er = eo + (size_t)b * 10240;
  unsigned short* ldsf = &lds[0][0];
#pragma unroll
  for (int i = 0; i < 5; ++i)
    gload16(er + (i * 256 + t) * 8, ldsf + (i * 256 + t) * 8);

  if (t < 64) {
    const float v0 = (t < 56) ? logits[(size_t)b * 64 + t] : 0.f;
    const int off[4] = {0, 20, 32, 44};
    const int wd[4]  = {20, 12, 12, 12};
    for (int g = 0; g < 4; ++g) {
      const bool in = (t >= off[g]) && (t < off[g] + wd[g]);
      float vv = in ? v0 : -1e30f;
      float m = vv;
#pragma unroll
      for (int o = 32; o; o >>= 1) m = fmaxf(m, __shfl_xor(m, o));
      float e = in ? __expf(vv - m) : 0.f;
      float s = e;
#pragma unroll
      for (int o = 32; o; o >>= 1) s += __shfl_xor(s, o);
      if (in) gsm[t] = e / s;
    }
  }
  __syncthreads();

  const int sec = t >> 6;
  const int h0 = (t & 63) * 8;
  float acc[8] = {0.f, 0.f, 0.f, 0.f, 0.f, 0.f, 0.f, 0.f};
  if (sec == 0) {
    for (int e = 0; e < 20; ++e) {
      const float w = gsm[e];
#pragma unroll
      for (int j = 0; j < 8; ++j) acc[j] += w * bf2f(lds[e][h0 + j]);
    }
  } else {
    const int goff = 20 + (sec - 1) * 12;
    const int ebase = 8 + (sec - 1) * 4;
    for (int tt = 0; tt < 4; ++tt) {
      const float w = gsm[goff + tt];
#pragma unroll
      for (int j = 0; j < 8; ++j) acc[j] += w * bf2f(lds[ebase + tt][h0 + j]);
    }
    for (int ss = 0; ss < 8; ++ss) {
      const float w = gsm[goff + 4 + ss];
#pragma unroll
      for (int j = 0; j < 8; ++j) acc[j] += w * bf2f(lds[ss][h0 + j]);
    }
  }
  unsigned short* ob = tin + (size_t)b * 2048 + sec * 512 + h0;
  ushort4 u0 = make_ushort4(f2bf(acc[0]), f2bf(acc[1]), f2bf(acc[2]), f2bf(acc[3]));
  ushort4 u1 = make_ushort4(f2bf(acc[4]), f2bf(acc[5]), f2bf(acc[6]), f2bf(acc[7]));
  *(ushort4*)ob = u0;
  *(ushort4*)(ob + 4) = u1;
}

// ---------------------------------------------------------------------------
// final dense: wave per (b, task)
// ---------------------------------------------------------------------------
__global__ __launch_bounds__(256) void outd_k(
    const unsigned short* __restrict__ t2,   // [2][8192][512]
    const float* __restrict__ Wd0, const float* __restrict__ bd0,
    const float* __restrict__ Wd1, const float* __restrict__ bd1,
    float* __restrict__ out)
{
  const int gid = blockIdx.x * 4 + (threadIdx.x >> 6);
  const int lane = threadIdx.x & 63;
  const int b = gid >> 1, task = gid & 1;
  const uint4 raw = *(const uint4*)(t2 + ((size_t)task * 8192 + b) * 512 + lane * 8);
  const unsigned short* rs = (const unsigned short*)&raw;
  float v[8];
#pragma unroll
  for (int j = 0; j < 8; ++j) v[j] = bf2f(rs[j]);
  const float* Wd = task ? Wd1 : Wd0;
  const float* bd = task ? bd1 : bd0;
  const int ncol = task ? 4 : 6;
  float* ob = task ? (out + (size_t)8192 * 6 + (size_t)b * 4) : (out + (size_t)b * 6);
  for (int c = 0; c < ncol; ++c) {
    float p = 0.f;
#pragma unroll
    for (int j = 0; j < 8; ++j) p += v[j] * Wd[(size_t)(lane * 8 + j) * ncol + c];
#pragma unroll
    for (int o = 32; o; o >>= 1) p += __shfl_xor(p, o);
    if (lane == 0) ob[c] = p + bd[c];
  }
}

// ---------------------------------------------------------------------------
extern "C" void kernel_launch(void* const* d_in, const int* in_sizes, int n_in,
                              void* d_out, int out_size, void* d_ws, size_t ws_size,
                              hipStream_t stream) {
  const float* x     = (const float*)d_in[0];
  const float* W1    = (const float*)d_in[1];
  const float* b1    = (const float*)d_in[2];
  const float* W2    = (const float*)d_in[3];
  const float* b2    = (const float*)d_in[4];
  const float* W3    = (const float*)d_in[5];
  const float* b3    = (const float*)d_in[6];
  const float* Wg_sh = (const float*)d_in[7];
  const float* bg_sh = (const float*)d_in[8];
  const float* Wg_sa = (const float*)d_in[9];
  const float* bg_sa = (const float*)d_in[10];
  const float* Wg_ra = (const float*)d_in[11];
  const float* bg_ra = (const float*)d_in[12];
  const float* Wg_ea = (const float*)d_in[13];
  const float* bg_ea = (const float*)d_in[14];
  const float* Wt1   = (const float*)d_in[15];
  const float* bt1   = (const float*)d_in[16];
  const float* Wt2   = (const float*)d_in[17];
  const float* bt2   = (const float*)d_in[18];
  const float* Wd0   = (const float*)d_in[19];
  const float* bd0   = (const float*)d_in[20];
  const float* Wd1   = (const float*)d_in[21];
  const float* bd1   = (const float*)d_in[22];
  float* out = (float*)d_out;

  const int B = 8192, D = 1024, H1 = 2048, H2 = 1024, H3 = 512;
  const int E = 20, TU1 = 1024, TU2 = 512, TIN = 2048;

  auto rnd = [](size_t n) { return (n + 255) & ~(size_t)255; };
  const size_t szTin = rnd((size_t)B * TIN * 2);
  const size_t szT1  = rnd((size_t)2 * B * TU1 * 2);
  const size_t szH1e = rnd((size_t)B * H1 * 2);

  char* w = (char*)d_ws;
  auto alloc = [&](size_t n) { char* p = w; w += rnd(n); return p; };
  unsigned short* xb   = (unsigned short*)alloc((size_t)B * D * 2);
  unsigned short* W1t  = (unsigned short*)alloc((size_t)E * H1 * D * 2);
  unsigned short* W2t  = (unsigned short*)alloc((size_t)E * H2 * H1 * 2);
  unsigned short* W3t  = (unsigned short*)alloc((size_t)E * H3 * H2 * 2);
  unsigned short* Wt1t = (unsigned short*)alloc((size_t)2 * TU1 * TIN * 2);
  unsigned short* Wt2t = (unsigned short*)alloc((size_t)2 * TU2 * TU1 * 2);
  float*          lgts = (float*)alloc((size_t)B * 64 * 4);
  unsigned short* eo   = (unsigned short*)alloc((size_t)E * B * H3 * 2);
  // h-region: h1 = 2 SINGLE-expert slots (67 MB), h2 = 4 single slots (67 MB)
  // -> resident set ~170 MB, fits the 256 MB L3. Towers alias the region.
  char* hreg = w;
  unsigned short* h1  = (unsigned short*)hreg;                        // [2][B][H1]
  unsigned short* h2  = (unsigned short*)(hreg + 2 * szH1e);          // [4][B][H2]
  unsigned short* tin = (unsigned short*)hreg;
  unsigned short* t1  = (unsigned short*)(hreg + szTin);
  unsigned short* t2  = (unsigned short*)(hreg + szTin + szT1);
  (void)in_sizes; (void)n_in; (void)out_size; (void)ws_size;

  prep_all<<<dim3(13312), 256, 0, stream>>>(
      W1, W2, W3, Wt1, Wt2, x,
      Wg_sh, bg_sh, Wg_sa, bg_sa, Wg_ra, bg_ra, Wg_ea, bg_ea,
      W1t, W2t, W3t, Wt1t, Wt2t, xb, lgts);

  // expert-single software pipeline: dual(k) = L1(expert k) + L2(expert k-1).
  // h1 2 parity slots; h2 slot e%4; L3 window (4 experts) after dual k=4w+4.
  for (int k = 0; k <= 20; ++k) {
    const bool has1 = (k < 20), has2 = (k > 0);
    const int split = has1 ? 256 : 0;
    const int total = split + (has2 ? 256 : 0);
    const int e1 = has1 ? k : 0;
    const int e2 = has2 ? (k - 1) : 0;
    const unsigned short* A1 = xb;
    const unsigned short* B1 = W1t + (size_t)e1 * H1 * D;
    const float* bb1 = b1 + (size_t)e1 * H1;
    unsigned short* O1 = h1 + (size_t)(e1 & 1) * B * H1;
    const unsigned short* A2 = h1 + (size_t)(e2 & 1) * B * H1;
    const unsigned short* B2 = W2t + (size_t)e2 * H2 * H1;
    const float* bb2 = b2 + (size_t)e2 * H2;
    unsigned short* O2 = h2 + (size_t)(e2 & 3) * B * H2;
    const int grid = total < 256 ? total : 256;
    gemm_dual<<<dim3(grid), 512, 0, stream>>>(
        A1, B1, bb1, O1, D, D, H1, H1 / 256, B / 256,
        0, (long)H1 * D, (long)H1, (long)B * H1,
        A2, B2, bb2, O2, H1, H1, H2, H2 / 256, B / 256,
        (long)B * H1, (long)H2 * H1, (long)H2, (long)B * H2,
        split, total);
    if (k >= 4 && (k % 4) == 0) {
      const int w2 = (k - 4) / 4;     // windows 0..4 (k = 4,8,12,16,20)
      gemm_l3<<<dim3(256), 512, 0, stream>>>(
          h2, W3t + (size_t)(4 * w2) * H3 * H2, b3 + (size_t)(4 * w2) * H3,
          eo + (size_t)(4 * w2) * H3,
          H2, H2, E * H3, H3 / 256, B / 256,
          (long)B * H2, (long)H3 * H2, (long)H3, (long)H3, 256);
    }
  }

  combine_k<<<dim3(B), 256, 0, stream>>>(eo, lgts, tin);

  gemm_tw<<<dim3(256), 512, 0, stream>>>(
      tin, Wt1t, bt1, t1, TIN, TIN, TU1, TU1 / 256, B / 256,
      0, (long)TU1 * TIN, (long)TU1, (long)B * TU1, 256);
  gemm_tw<<<dim3(128), 512, 0, stream>>>(
      t1, Wt2t, bt2, t2, TU1, TU1, TU2, TU2 / 256, B / 256,
      (long)B * TU1, (long)TU2 * TU1, (long)TU2, (long)B * TU2, 128);

  outd_k<<<dim3(B * 2 / 4), 256, 0, stream>>>(t2, Wd0, bd0, Wd1, bd1, out);
}

// Round 19
// 2012.535 us; speedup vs baseline: 1.3334x; 1.3334x over previous
//
#include <hip/hip_runtime.h>

#define DEV __device__ __forceinline__

typedef __bf16 bf16x8 __attribute__((ext_vector_type(8)));
typedef float f32x4 __attribute__((ext_vector_type(4)));

DEV unsigned short f2bf(float f) {
  union { float f; unsigned u; } v; v.f = f;
  unsigned r = v.u + 0x7FFFu + ((v.u >> 16) & 1u);
  return (unsigned short)(r >> 16);
}
DEV float bf2f(unsigned short h) {
  union { float f; unsigned u; } v; v.u = ((unsigned)h) << 16;
  return v.f;
}

// async global->LDS, 16B per lane.
DEV void gload16(const void* g, void* l) {
  __builtin_amdgcn_global_load_lds(
      (__attribute__((address_space(1))) void*)(g),
      (__attribute__((address_space(3))) void*)(l), 16, 0, 0);
}

#define MFMA16(a, b, c) __builtin_amdgcn_mfma_f32_16x16x32_bf16((a), (b), (c), 0, 0, 0)

// ---------------------------------------------------------------------------
// Persistent 256x256 GEMM (PROVEN round-5 k-loop; persistent wrapper from
// round 13). Do not touch.
// ---------------------------------------------------------------------------
struct TileCtx {
  const char* gA;
  const char* gB;
  size_t stepA, stepB;
  const float* bias;
  unsigned short* Out;
  int nkt, ldo, n0, m0;
};

DEV TileCtx tile_decode(int bid, int nwg,
    const unsigned short* A, const unsigned short* Bt, const float* bias,
    unsigned short* Out, int K, int lda, int ldo, int nbx, int nby,
    long sA, long sB, long sBias, long sOut, int rr, int ch)
{
  int wg = bid;
  {
    const int q = nwg >> 3, r = nwg & 7;
    const int xcd = wg & 7, pos = wg >> 3;
    wg = (xcd < r ? xcd * (q + 1) : r * (q + 1) + (xcd - r) * q) + pos;
  }
  const int per_z = nbx * nby;
  const int z  = wg / per_z;
  const int rz = wg - z * per_z;
  const int by = rz / nbx;
  const int bx = rz - by * nbx;

  TileCtx c;
  c.nkt = K >> 6;
  c.ldo = ldo;
  c.m0  = by * 256;
  c.n0  = bx * 256;
  c.bias = bias + (size_t)z * sBias;
  c.Out  = Out  + (size_t)z * sOut;
  c.gA = (const char*)(A  + (size_t)z * sA) + ((size_t)(c.m0 + rr) * lda) * 2 + ch * 16;
  c.gB = (const char*)(Bt + (size_t)z * sB) + ((size_t)(c.n0 + rr) * K)   * 2 + ch * 16;
  c.stepA = (size_t)64 * lda * 2;
  c.stepB = (size_t)64 * K * 2;
  return c;
}

DEV void gemm_persist(
    const unsigned short* A1, const unsigned short* Bt1, const float* bias1,
    unsigned short* O1, int K1, int lda1, int ldo1, int nbx1, int nby1,
    long sA1, long sB1, long sBias1, long sO1,
    const unsigned short* A2, const unsigned short* Bt2, const float* bias2,
    unsigned short* O2, int K2, int lda2, int ldo2, int nbx2, int nby2,
    long sA2, long sB2, long sBias2, long sO2,
    int split, int total)
{
  __shared__ alignas(16) char sm[2][65536];
  char* smb = &sm[0][0];

  const int tid  = threadIdx.x;
  const int lane = tid & 63;
  const int wid  = tid >> 6;
  const int wm   = wid >> 2, wn = wid & 3;
  const int rr = tid >> 3;
  const int ch = (tid & 7) ^ (rr & 7);
  const int koff0 = (((lane >> 4) << 4) ^ ((lane & 7) << 4));
  const int aRow  = wm * 128 + (lane & 15);
  const int bRow  = wn * 64  + (lane & 15);

  auto dec = [&](int tix) -> TileCtx {
    if (tix < split)
      return tile_decode(tix, split, A1, Bt1, bias1, O1, K1, lda1, ldo1,
                         nbx1, nby1, sA1, sB1, sBias1, sO1, rr, ch);
    return tile_decode(tix - split, total - split, A2, Bt2, bias2, O2, K2,
                       lda2, ldo2, nbx2, nby2, sA2, sB2, sBias2, sO2, rr, ch);
  };
  auto SA = [&](const TileCtx& c, int buf, int kt, int jh) {
    const char* s = c.gA + (size_t)kt * 128 + (2 * jh) * c.stepA;
    char* l = smb + buf * 65536 + tid * 16 + (2 * jh) * 8192;
    gload16(s, l);
    gload16(s + c.stepA, l + 8192);
  };
  auto SB = [&](const TileCtx& c, int buf, int kt, int jh) {
    const char* s = c.gB + (size_t)kt * 128 + (2 * jh) * c.stepB;
    char* l = smb + buf * 65536 + 32768 + tid * 16 + (2 * jh) * 8192;
    gload16(s, l);
    gload16(s + c.stepB, l + 8192);
  };
  auto STAGE0 = [&](const TileCtx& c) {
    SA(c, 0, 0, 0); SA(c, 0, 0, 1); SB(c, 0, 0, 0); SB(c, 0, 0, 1);
  };

  int tix = (int)blockIdx.x;
  if (tix >= total) return;
  TileCtx cur = dec(tix);
  STAGE0(cur);

  f32x4 acc[8][4];
  const f32x4 fz = {0.f, 0.f, 0.f, 0.f};

  while (true) {
#pragma unroll
    for (int i = 0; i < 8; ++i)
#pragma unroll
      for (int j = 0; j < 4; ++j) acc[i][j] = fz;

    const int nkt = cur.nkt;
    for (int kt = 0; kt < nkt; ++kt) {
      const int cb = kt & 1, nb = cb ^ 1;
      const bool pre = (kt + 1 < nkt);
      if (pre) {
        SA(cur, nb, kt + 1, 0);
        asm volatile("s_waitcnt vmcnt(2)" ::: "memory");
      } else {
        asm volatile("s_waitcnt vmcnt(0)" ::: "memory");
      }
      __builtin_amdgcn_s_barrier();
      __builtin_amdgcn_sched_barrier(0);

      const char* pA = smb + cb * 65536 + aRow * 128;
      const char* pB = smb + cb * 65536 + 32768 + bRow * 128;
      bf16x8 a0[4], a1[4], b0[4], b1[4];

      // ---- phase 0: mi 0-3, ks0
      {
#pragma unroll
        for (int i = 0; i < 4; ++i) a0[i] = *(const bf16x8*)(pA + i * 2048 + koff0);
#pragma unroll
        for (int n = 0; n < 4; ++n) b0[n] = *(const bf16x8*)(pB + n * 2048 + koff0);
        if (pre) SA(cur, nb, kt + 1, 1);
        asm volatile("s_waitcnt lgkmcnt(0)" ::: "memory");
        __builtin_amdgcn_sched_barrier(0);
        __builtin_amdgcn_s_setprio(1);
#pragma unroll
        for (int i = 0; i < 4; ++i)
#pragma unroll
          for (int n = 0; n < 4; ++n) acc[i][n] = MFMA16(a0[i], b0[n], acc[i][n]);
        __builtin_amdgcn_s_setprio(0);
        __builtin_amdgcn_sched_barrier(0);
        __builtin_amdgcn_s_barrier();
        __builtin_amdgcn_sched_barrier(0);
      }
      // ---- phase 1: mi 4-7, ks0
      {
#pragma unroll
        for (int i = 0; i < 4; ++i) a1[i] = *(const bf16x8*)(pA + (i + 4) * 2048 + koff0);
        if (pre) { SB(cur, nb, kt + 1, 0); SB(cur, nb, kt + 1, 1); }
        asm volatile("s_waitcnt lgkmcnt(0)" ::: "memory");
        __builtin_amdgcn_sched_barrier(0);
        __builtin_amdgcn_s_setprio(1);
#pragma unroll
        for (int i = 0; i < 4; ++i)
#pragma unroll
          for (int n = 0; n < 4; ++n) acc[i + 4][n] = MFMA16(a1[i], b0[n], acc[i + 4][n]);
        __builtin_amdgcn_s_setprio(0);
        __builtin_amdgcn_sched_barrier(0);
        __builtin_amdgcn_s_barrier();
        __builtin_amdgcn_sched_barrier(0);
      }
      // ---- phase 2: mi 0-3, ks1
      {
        const int ko = koff0 ^ 64;
#pragma unroll
        for (int i = 0; i < 4; ++i) a0[i] = *(const bf16x8*)(pA + i * 2048 + ko);
#pragma unroll
        for (int n = 0; n < 4; ++n) b1[n] = *(const bf16x8*)(pB + n * 2048 + ko);
        asm volatile("s_waitcnt lgkmcnt(0)" ::: "memory");
        __builtin_amdgcn_sched_barrier(0);
        __builtin_amdgcn_s_setprio(1);
#pragma unroll
        for (int i = 0; i < 4; ++i)
#pragma unroll
          for (int n = 0; n < 4; ++n) acc[i][n] = MFMA16(a0[i], b1[n], acc[i][n]);
        __builtin_amdgcn_s_setprio(0);
        __builtin_amdgcn_sched_barrier(0);
        __builtin_amdgcn_s_barrier();
        __builtin_amdgcn_sched_barrier(0);
      }
      // ---- phase 3: mi 4-7, ks1
      {
        const int ko = koff0 ^ 64;
#pragma unroll
        for (int i = 0; i < 4; ++i) a1[i] = *(const bf16x8*)(pA + (i + 4) * 2048 + ko);
        asm volatile("s_waitcnt lgkmcnt(0)" ::: "memory");
        __builtin_amdgcn_sched_barrier(0);
        __builtin_amdgcn_s_setprio(1);
#pragma unroll
        for (int i = 0; i < 4; ++i)
#pragma unroll
          for (int n = 0; n < 4; ++n) acc[i + 4][n] = MFMA16(a1[i], b1[n], acc[i + 4][n]);
        __builtin_amdgcn_s_setprio(0);
        __builtin_amdgcn_sched_barrier(0);
        __builtin_amdgcn_s_barrier();
        __builtin_amdgcn_sched_barrier(0);
      }
    }

    // cross-tile prefetch before the epilogue stores
    const int nxt = tix + (int)gridDim.x;
    const bool has = nxt < total;
    TileCtx nc;
    if (has) { nc = dec(nxt); STAGE0(nc); }

    // epilogue: bias + lrelu + bf16 store
#pragma unroll
    for (int ni = 0; ni < 4; ++ni) {
      const int c = cur.n0 + wn * 64 + ni * 16 + (lane & 15);
      const float bv = cur.bias[c];
#pragma unroll
      for (int mi = 0; mi < 8; ++mi) {
        const int r0 = cur.m0 + wm * 128 + mi * 16 + ((lane >> 4) << 2);
#pragma unroll
        for (int j = 0; j < 4; ++j) {
          float v = acc[mi][ni][j] + bv;
          v = v >= 0.f ? v : 0.1f * v;
          cur.Out[(size_t)(r0 + j) * cur.ldo + c] = f2bf(v);
        }
      }
    }

    if (!has) return;
    cur = nc;
    tix = nxt;
  }
}

__global__ __launch_bounds__(512) void gemm_dual(
    const unsigned short* A1, const unsigned short* Bt1, const float* bias1,
    unsigned short* O1, int K1, int lda1, int ldo1, int nbx1, int nby1,
    long sA1, long sB1, long sBias1, long sO1,
    const unsigned short* A2, const unsigned short* Bt2, const float* bias2,
    unsigned short* O2, int K2, int lda2, int ldo2, int nbx2, int nby2,
    long sA2, long sB2, long sBias2, long sO2,
    int split, int total)
{
  gemm_persist(A1, Bt1, bias1, O1, K1, lda1, ldo1, nbx1, nby1,
               sA1, sB1, sBias1, sO1,
               A2, Bt2, bias2, O2, K2, lda2, ldo2, nbx2, nby2,
               sA2, sB2, sBias2, sO2, split, total);
}

#define GEMM_DEF(NAME)                                                        \
__global__ __launch_bounds__(512) void NAME(                                  \
    const unsigned short* A, const unsigned short* Bt, const float* bias,     \
    unsigned short* Out, int K, int lda, int ldo, int nbx, int nby,           \
    long sA, long sB, long sBias, long sOut, int total) {                     \
  gemm_persist(A, Bt, bias, Out, K, lda, ldo, nbx, nby, sA, sB, sBias, sOut,  \
               A, Bt, bias, Out, K, lda, ldo, nbx, nby, sA, sB, sBias, sOut,  \
               total, total);                                                 \
}
GEMM_DEF(gemm_l3)
GEMM_DEF(gemm_tw)

// ---------------------------------------------------------------------------
// gate bias gather (concatenated column space: sh20|sa12|ra12|ea12, pad 0)
// ---------------------------------------------------------------------------
DEV float gateB(const float* bsh, const float* bsa, const float* bra,
                const float* bea, int c) {
  if (c < 20) return bsh[c];
  if (c < 32) return bsa[c - 20];
  if (c < 44) return bra[c - 32];
  if (c < 56) return bea[c - 44];
  return 0.f;
}

// ---------------------------------------------------------------------------
// prep_all: gate logits + all fp32->bf16 conversions in ONE launch.
//   [0,128):         gate logits — fp32 micro-GEMM, hoisted W pointers +
//                    register prefetch of next K-tile
//   [128,12288):     weight transposes — 2 k-tiles per block, two-phase LDS
//   [12288,13312):   x straight convert, 2 tiles per block
// ---------------------------------------------------------------------------
__global__ __launch_bounds__(256) void prep_all(
    const float* __restrict__ W1,  const float* __restrict__ W2,
    const float* __restrict__ W3,  const float* __restrict__ Wt1,
    const float* __restrict__ Wt2, const float* __restrict__ x,
    const float* __restrict__ Wsh, const float* __restrict__ bsh,
    const float* __restrict__ Wsa, const float* __restrict__ bsa,
    const float* __restrict__ Wra, const float* __restrict__ bra,
    const float* __restrict__ Wea, const float* __restrict__ bea,
    unsigned short* __restrict__ W1t,  unsigned short* __restrict__ W2t,
    unsigned short* __restrict__ W3t,  unsigned short* __restrict__ Wt1t,
    unsigned short* __restrict__ Wt2t, unsigned short* __restrict__ xb,
    float* __restrict__ logits)
{
  const int id = blockIdx.x;
  const int t  = threadIdx.x;

  if (id < 128) {
    __shared__ alignas(16) float smg[4096];          // sx[32][64] | sw[32][64]
    float (*sx)[64] = (float (*)[64])smg;
    float (*sw)[64] = (float (*)[64])(smg + 2048);
    const int b0 = id * 64;
    const int tr = t >> 4, tc = t & 15;

    const int xr = t >> 3;
    const int xc = (t & 7) * 4;
    const int c4 = tc * 4;
    const float* wb = Wsh; int wo = 0, gw = 20; bool wval = true;
    if (c4 < 20)      { wb = Wsh; wo = c4;      gw = 20; }
    else if (c4 < 32) { wb = Wsa; wo = c4 - 20; gw = 12; }
    else if (c4 < 44) { wb = Wra; wo = c4 - 32; gw = 12; }
    else if (c4 < 56) { wb = Wea; wo = c4 - 44; gw = 12; }
    else              { wval = false; }
    const int wr0 = t >> 4;

    float4 xv0, xv1;
    float w0[4], w1[4];
    auto ldx = [&](int k0) {
      xv0 = *(const float4*)(x + (size_t)(b0 + xr) * 1024 + k0 + xc);
      xv1 = *(const float4*)(x + (size_t)(b0 + 32 + xr) * 1024 + k0 + xc);
    };
    auto ldw = [&](int k0) {
#pragma unroll
      for (int j = 0; j < 4; ++j) {
        w0[j] = wval ? wb[(size_t)(k0 + wr0) * gw + wo + j] : 0.f;
        w1[j] = wval ? wb[(size_t)(k0 + 16 + wr0) * gw + wo + j] : 0.f;
      }
    };
    ldx(0); ldw(0);

    float acc[4][4] = {};
    for (int kt = 0; kt < 32; ++kt) {
      __syncthreads();
      sx[xc + 0][xr] = xv0.x; sx[xc + 1][xr] = xv0.y;
      sx[xc + 2][xr] = xv0.z; sx[xc + 3][xr] = xv0.w;
      sx[xc + 0][32 + xr] = xv1.x; sx[xc + 1][32 + xr] = xv1.y;
      sx[xc + 2][32 + xr] = xv1.z; sx[xc + 3][32 + xr] = xv1.w;
#pragma unroll
      for (int j = 0; j < 4; ++j) {
        sw[wr0][c4 + j]      = w0[j];
        sw[16 + wr0][c4 + j] = w1[j];
      }
      if (kt + 1 < 32) { ldx((kt + 1) * 32); ldw((kt + 1) * 32); }
      __syncthreads();
#pragma unroll
      for (int kk = 0; kk < 32; ++kk) {
        const float4 rx = *(const float4*)&sx[kk][tr * 4];
        const float4 wv = *(const float4*)&sw[kk][tc * 4];
#pragma unroll
        for (int i = 0; i < 4; ++i) {
          const float xv = (i == 0) ? rx.x : (i == 1) ? rx.y : (i == 2) ? rx.z : rx.w;
          acc[i][0] += xv * wv.x; acc[i][1] += xv * wv.y;
          acc[i][2] += xv * wv.z; acc[i][3] += xv * wv.w;
        }
      }
    }
    float bv[4];
#pragma unroll
    for (int j = 0; j < 4; ++j) bv[j] = gateB(bsh, bsa, bra, bea, c4 + j);
#pragma unroll
    for (int i = 0; i < 4; ++i) {
      float4 o;
      o.x = acc[i][0] + bv[0]; o.y = acc[i][1] + bv[1];
      o.z = acc[i][2] + bv[2]; o.w = acc[i][3] + bv[3];
      *(float4*)&logits[(size_t)(b0 + tr * 4 + i) * 64 + tc * 4] = o;
    }
    return;
  }

  if (id >= 12288) {                 // x straight convert, 2 tiles/block
    const int base = (id - 12288) * 2;
#pragma unroll
    for (int jj = 0; jj < 2; ++jj) {
      const int lt = base + jj;
      const int r0 = (lt >> 4) * 64, c0 = (lt & 15) * 64;
#pragma unroll
      for (int i = 0; i < 4; ++i) {
        const int row = r0 + i * 16 + (t >> 4);
        const int col = c0 + (t & 15) * 4;
        const float4 v = *(const float4*)(x + (size_t)row * 1024 + col);
        ushort4 u = make_ushort4(f2bf(v.x), f2bf(v.y), f2bf(v.z), f2bf(v.w));
        *(ushort4*)(xb + (size_t)row * 1024 + col) = u;
      }
    }
    return;
  }

  // ---- weight transposes: 2 k-tiles (128 k-rows x 64 n-cols) per block
  const int g = id - 128;
  const float* src; unsigned short* dst; int K, N, local;
  if (g < 5120)       { src = W1;  dst = W1t;  K = 1024; N = 2048; local = g; }
  else if (g < 10240) { src = W2;  dst = W2t;  K = 2048; N = 1024; local = g - 5120; }
  else if (g < 11520) { src = W3;  dst = W3t;  K = 1024; N = 512;  local = g - 10240; }
  else if (g < 12032) { src = Wt1; dst = Wt1t; K = 2048; N = 1024; local = g - 11520; }
  else                { src = Wt2; dst = Wt2t; K = 1024; N = 512;  local = g - 12032; }

  const int npk = K >> 7, nnt = N >> 6;
  const int per_z = npk * nnt;
  const int z   = local / per_z;
  const int rem = local - z * per_z;
  const int pk  = rem % npk;
  const int n0  = (rem / npk) * 64;
  src += (size_t)z * K * N;
  dst += (size_t)z * K * N;

  __shared__ unsigned short ldsT[64 * 65];
  const int cr = t >> 4, cc = (t & 15) * 4;
  const int nrow = t >> 2, ks = (t & 3) * 16;
#pragma unroll
  for (int jj = 0; jj < 2; ++jj) {
    const int k0 = pk * 128 + jj * 64;
    if (jj) __syncthreads();
#pragma unroll
    for (int i = 0; i < 4; ++i) {
      const int row = i * 16 + cr;
      const float4 v = *(const float4*)(src + (size_t)(k0 + row) * N + n0 + cc);
      ldsT[(cc + 0) * 65 + row] = f2bf(v.x);
      ldsT[(cc + 1) * 65 + row] = f2bf(v.y);
      ldsT[(cc + 2) * 65 + row] = f2bf(v.z);
      ldsT[(cc + 3) * 65 + row] = f2bf(v.w);
    }
    __syncthreads();
    unsigned short vbuf[16];
#pragma unroll
    for (int j = 0; j < 16; ++j) vbuf[j] = ldsT[nrow * 65 + ks + j];
    unsigned short* dp = dst + (size_t)(n0 + nrow) * K + k0 + ks;
    *(uint4*)dp       = *(const uint4*)&vbuf[0];
    *(uint4*)(dp + 8) = *(const uint4*)&vbuf[8];
  }
}

// ---------------------------------------------------------------------------
// combine: async eo-row staging overlapped with softmax, then gated sums.
// ---------------------------------------------------------------------------
__global__ __launch_bounds__(256) void combine_k(
    const unsigned short* __restrict__ eo,   // [8192][10240]
    const float* __restrict__ logits,        // [8192][64]
    unsigned short* __restrict__ tin)        // [8192][2048]
{
  const int b = blockIdx.x;
  const int t = threadIdx.x;
  __shared__ alignas(16) unsigned short lds[20][512];
  __shared__ float gsm[56];
  const unsigned short* er = eo + (size_t)b * 10240;
  unsigned short* ldsf = &lds[0][0];
#pragma unroll
  for (int i = 0; i < 5; ++i)
    gload16(er + (i * 256 + t) * 8, ldsf + (i * 256 + t) * 8);

  if (t < 64) {
    const float v0 = (t < 56) ? logits[(size_t)b * 64 + t] : 0.f;
    const int off[4] = {0, 20, 32, 44};
    const int wd[4]  = {20, 12, 12, 12};
    for (int g = 0; g < 4; ++g) {
      const bool in = (t >= off[g]) && (t < off[g] + wd[g]);
      float vv = in ? v0 : -1e30f;
      float m = vv;
#pragma unroll
      for (int o = 32; o; o >>= 1) m = fmaxf(m, __shfl_xor(m, o));
      float e = in ? __expf(vv - m) : 0.f;
      float s = e;
#pragma unroll
      for (int o = 32; o; o >>= 1) s += __shfl_xor(s, o);
      if (in) gsm[t] = e / s;
    }
  }
  __syncthreads();

  const int sec = t >> 6;
  const int h0 = (t & 63) * 8;
  float acc[8] = {0.f, 0.f, 0.f, 0.f, 0.f, 0.f, 0.f, 0.f};
  if (sec == 0) {
    for (int e = 0; e < 20; ++e) {
      const float w = gsm[e];
#pragma unroll
      for (int j = 0; j < 8; ++j) acc[j] += w * bf2f(lds[e][h0 + j]);
    }
  } else {
    const int goff = 20 + (sec - 1) * 12;
    const int ebase = 8 + (sec - 1) * 4;
    for (int tt = 0; tt < 4; ++tt) {
      const float w = gsm[goff + tt];
#pragma unroll
      for (int j = 0; j < 8; ++j) acc[j] += w * bf2f(lds[ebase + tt][h0 + j]);
    }
    for (int ss = 0; ss < 8; ++ss) {
      const float w = gsm[goff + 4 + ss];
#pragma unroll
      for (int j = 0; j < 8; ++j) acc[j] += w * bf2f(lds[ss][h0 + j]);
    }
  }
  unsigned short* ob = tin + (size_t)b * 2048 + sec * 512 + h0;
  ushort4 u0 = make_ushort4(f2bf(acc[0]), f2bf(acc[1]), f2bf(acc[2]), f2bf(acc[3]));
  ushort4 u1 = make_ushort4(f2bf(acc[4]), f2bf(acc[5]), f2bf(acc[6]), f2bf(acc[7]));
  *(ushort4*)ob = u0;
  *(ushort4*)(ob + 4) = u1;
}

// ---------------------------------------------------------------------------
// final dense: wave per (b, task)
// ---------------------------------------------------------------------------
__global__ __launch_bounds__(256) void outd_k(
    const unsigned short* __restrict__ t2,   // [2][8192][512]
    const float* __restrict__ Wd0, const float* __restrict__ bd0,
    const float* __restrict__ Wd1, const float* __restrict__ bd1,
    float* __restrict__ out)
{
  const int gid = blockIdx.x * 4 + (threadIdx.x >> 6);
  const int lane = threadIdx.x & 63;
  const int b = gid >> 1, task = gid & 1;
  const uint4 raw = *(const uint4*)(t2 + ((size_t)task * 8192 + b) * 512 + lane * 8);
  const unsigned short* rs = (const unsigned short*)&raw;
  float v[8];
#pragma unroll
  for (int j = 0; j < 8; ++j) v[j] = bf2f(rs[j]);
  const float* Wd = task ? Wd1 : Wd0;
  const float* bd = task ? bd1 : bd0;
  const int ncol = task ? 4 : 6;
  float* ob = task ? (out + (size_t)8192 * 6 + (size_t)b * 4) : (out + (size_t)b * 6);
  for (int c = 0; c < ncol; ++c) {
    float p = 0.f;
#pragma unroll
    for (int j = 0; j < 8; ++j) p += v[j] * Wd[(size_t)(lane * 8 + j) * ncol + c];
#pragma unroll
    for (int o = 32; o; o >>= 1) p += __shfl_xor(p, o);
    if (lane == 0) ob[c] = p + bd[c];
  }
}

// ---------------------------------------------------------------------------
extern "C" void kernel_launch(void* const* d_in, const int* in_sizes, int n_in,
                              void* d_out, int out_size, void* d_ws, size_t ws_size,
                              hipStream_t stream) {
  const float* x     = (const float*)d_in[0];
  const float* W1    = (const float*)d_in[1];
  const float* b1    = (const float*)d_in[2];
  const float* W2    = (const float*)d_in[3];
  const float* b2    = (const float*)d_in[4];
  const float* W3    = (const float*)d_in[5];
  const float* b3    = (const float*)d_in[6];
  const float* Wg_sh = (const float*)d_in[7];
  const float* bg_sh = (const float*)d_in[8];
  const float* Wg_sa = (const float*)d_in[9];
  const float* bg_sa = (const float*)d_in[10];
  const float* Wg_ra = (const float*)d_in[11];
  const float* bg_ra = (const float*)d_in[12];
  const float* Wg_ea = (const float*)d_in[13];
  const float* bg_ea = (const float*)d_in[14];
  const float* Wt1   = (const float*)d_in[15];
  const float* bt1   = (const float*)d_in[16];
  const float* Wt2   = (const float*)d_in[17];
  const float* bt2   = (const float*)d_in[18];
  const float* Wd0   = (const float*)d_in[19];
  const float* bd0   = (const float*)d_in[20];
  const float* Wd1   = (const float*)d_in[21];
  const float* bd1   = (const float*)d_in[22];
  float* out = (float*)d_out;

  const int B = 8192, D = 1024, H1 = 2048, H2 = 1024, H3 = 512;
  const int E = 20, TU1 = 1024, TU2 = 512, TIN = 2048;

  auto rnd = [](size_t n) { return (n + 255) & ~(size_t)255; };
  const size_t szTin = rnd((size_t)B * TIN * 2);
  const size_t szT1  = rnd((size_t)2 * B * TU1 * 2);
  const size_t szH1e = rnd((size_t)B * H1 * 2);

  char* w = (char*)d_ws;
  auto alloc = [&](size_t n) { char* p = w; w += rnd(n); return p; };
  unsigned short* xb   = (unsigned short*)alloc((size_t)B * D * 2);
  unsigned short* W1t  = (unsigned short*)alloc((size_t)E * H1 * D * 2);
  unsigned short* W2t  = (unsigned short*)alloc((size_t)E * H2 * H1 * 2);
  unsigned short* W3t  = (unsigned short*)alloc((size_t)E * H3 * H2 * 2);
  unsigned short* Wt1t = (unsigned short*)alloc((size_t)2 * TU1 * TIN * 2);
  unsigned short* Wt2t = (unsigned short*)alloc((size_t)2 * TU2 * TU1 * 2);
  float*          lgts = (float*)alloc((size_t)B * 64 * 4);
  unsigned short* eo   = (unsigned short*)alloc((size_t)E * B * H3 * 2);
  // h-region: h1 = 2 pair-buffers x 2 experts (134 MB), h2 = 4 slots (67 MB).
  // towers (tin/t1/t2, 85 MB) alias the region after experts complete.
  char* hreg = w;
  unsigned short* h1  = (unsigned short*)hreg;                        // [2][2][B][H1]
  unsigned short* h2  = (unsigned short*)(hreg + 4 * szH1e);          // [4][B][H2]
  unsigned short* tin = (unsigned short*)hreg;
  unsigned short* t1  = (unsigned short*)(hreg + szTin);
  unsigned short* t2  = (unsigned short*)(hreg + szTin + szT1);
  (void)in_sizes; (void)n_in; (void)out_size; (void)ws_size;

  prep_all<<<dim3(13312), 256, 0, stream>>>(
      W1, W2, W3, Wt1, Wt2, x,
      Wg_sh, bg_sh, Wg_sa, bg_sa, Wg_ra, bg_ra, Wg_ea, bg_ea,
      W1t, W2t, W3t, Wt1t, Wt2t, xb, lgts);

  // software-pipelined experts (PAIRS, best measured config — round 17):
  // launch k packs L1(pair k) + L2(pair k-1); persistent grid 256.
  for (int k = 0; k <= 10; ++k) {
    const bool has1 = (k < 10), has2 = (k > 0);
    const int split = has1 ? 512 : 0;
    const int total = split + (has2 ? 256 : 0);
    const int p1 = k, p2 = k - 1;
    const unsigned short* A1 = xb;
    const unsigned short* B1 = W1t + (size_t)(2 * (has1 ? p1 : 0)) * H1 * D;
    const float* bb1 = b1 + (size_t)(2 * (has1 ? p1 : 0)) * H1;
    unsigned short* O1 = h1 + (size_t)((has1 ? p1 : 0) & 1) * 2 * B * H1;
    const unsigned short* A2 = h1 + (size_t)((has2 ? p2 : 0) & 1) * 2 * B * H1;
    const unsigned short* B2 = W2t + (size_t)(2 * (has2 ? p2 : 0)) * H2 * H1;
    const float* bb2 = b2 + (size_t)(2 * (has2 ? p2 : 0)) * H2;
    unsigned short* O2 = h2 + (size_t)((2 * (has2 ? p2 : 0)) & 3) * B * H2;
    const int grid = total < 256 ? total : 256;
    gemm_dual<<<dim3(grid), 512, 0, stream>>>(
        A1, B1, bb1, O1, D, D, H1, H1 / 256, B / 256,
        0, (long)H1 * D, (long)H1, (long)B * H1,
        A2, B2, bb2, O2, H1, H1, H2, H2 / 256, B / 256,
        (long)B * H1, (long)H2 * H1, (long)H2, (long)B * H2,
        split, total);
    if (k >= 2 && (k & 1) == 0) {
      const int w2 = (k - 2) / 2;
      gemm_l3<<<dim3(256), 512, 0, stream>>>(
          h2, W3t + (size_t)(4 * w2) * H3 * H2, b3 + (size_t)(4 * w2) * H3,
          eo + (size_t)(4 * w2) * H3,
          H2, H2, E * H3, H3 / 256, B / 256,
          (long)B * H2, (long)H3 * H2, (long)H3, (long)H3, 256);
    }
  }

  combine_k<<<dim3(B), 256, 0, stream>>>(eo, lgts, tin);

  gemm_tw<<<dim3(256), 512, 0, stream>>>(
      tin, Wt1t, bt1, t1, TIN, TIN, TU1, TU1 / 256, B / 256,
      0, (long)TU1 * TIN, (long)TU1, (long)B * TU1, 256);
  gemm_tw<<<dim3(128), 512, 0, stream>>>(
      t1, Wt2t, bt2, t2, TU1, TU1, TU2, TU2 / 256, B / 256,
      (long)B * TU1, (long)TU2 * TU1, (long)TU2, (long)B * TU2, 128);

  outd_k<<<dim3(B * 2 / 4), 256, 0, stream>>>(t2, Wd0, bd0, Wd1, bd1, out);
}